// Round 6
// baseline (338.691 us; speedup 1.0000x reference)
//
#include <hip/hip_runtime.h>
#include <hip/hip_bf16.h>

// out[m, f] = sum_e cos(x[m, e] + theta[e & 7]) * W[f, e]
// M = 65536, N = K = 512.  bf16 MFMA GEMM, A = cos(x+theta) fused in staging.
//
// Block = 64x512 output stripe (full N -> x read exactly once from HBM).
// A: full 64x512 bf16 tile in 64 KB LDS (XOR-swizzled), ONE barrier.
//    2 blocks resident per CU -> stage of next block overlaps compute.
// B: W pre-packed in d_ws in MFMA-fragment-major order -> every fragment load
//    is one fully-coalesced 16B/lane dwordx4 (8 x 128B lines per wave).
//    BM=64 halves per-N-column B re-reads vs BM=32 (L2 traffic ~15 us).
// K loop: fully unrolled 16 steps, 2-deep B / 1-deep A register prefetch,
// sched_barrier(0) per step pins issue order -> counted vmcnt/lgkmcnt waits.

typedef __attribute__((ext_vector_type(8))) short short8;   // 8 x bf16
typedef __attribute__((ext_vector_type(4))) float f32x4;    // MFMA acc frag

static constexpr int KD  = 512;
static constexpr int ND  = 512;
static constexpr int BM  = 64;
static constexpr int NKF = 16;           // K steps of 32

static __device__ __forceinline__ unsigned short f2bf(float f) {
    unsigned int b = __builtin_bit_cast(unsigned int, f);
    b += 0x7FFFu + ((b >> 16) & 1u);
    return (unsigned short)(b >> 16);
}

// cos via v_cos_f32: input in revolutions, explicit fract for range safety.
static __device__ __forceinline__ float fast_cos_rev(float rev) {
    float r = rev - __builtin_floorf(rev);
    float c;
    asm("v_cos_f32 %0, %1" : "=v"(c) : "v"(r));
    return c;
}

// Pack W into MFMA-fragment-major bf16:
//   WbF[((n_blk*16 + kf)*64 + lane)*8 + j] =
//       bf16( W[n_blk*16 + (lane&15)][kf*32 + (lane>>4)*8 + j] )
__global__ void cvt_w_frag(const float* __restrict__ W,
                           unsigned short* __restrict__ WbF) {
    const int i    = blockIdx.x * 256 + threadIdx.x;  // 0..32767 fragments
    const int lane = i & 63;
    const int kf   = (i >> 6) & 15;
    const int nblk = i >> 10;                         // 0..31
    const int row  = nblk * 16 + (lane & 15);         // f index
    const int col  = kf * 32 + (lane >> 4) * 8;       // e index
    const float* p = W + (size_t)row * KD + col;
    float4 w0 = *reinterpret_cast<const float4*>(p);
    float4 w1 = *reinterpret_cast<const float4*>(p + 4);
    short8 t8;
    t8[0] = (short)f2bf(w0.x); t8[1] = (short)f2bf(w0.y);
    t8[2] = (short)f2bf(w0.z); t8[3] = (short)f2bf(w0.w);
    t8[4] = (short)f2bf(w1.x); t8[5] = (short)f2bf(w1.y);
    t8[6] = (short)f2bf(w1.z); t8[7] = (short)f2bf(w1.w);
    *reinterpret_cast<short8*>(WbF + (size_t)i * 8) = t8;
}

template <bool PRECVT>
__global__ __launch_bounds__(512, 4)
void fused_qgemm(const float* __restrict__ x, const float* __restrict__ theta,
                 const float* __restrict__ W, const unsigned short* __restrict__ WbF,
                 float* __restrict__ out) {
    __shared__ unsigned short Alds[BM * KD];   // 64 KB, row pitch 1024 B, swizzled

    const int tid  = threadIdx.x;
    const int lane = tid & 63;
    const int wave = tid >> 6;                 // 0..7 -> n0 = wave*64
    const int m0   = blockIdx.x * BM;
    const int n0   = wave * 64;

    const int frow = lane & 15;                // fragment row/col index
    const int fkg  = lane >> 4;                // k-group 0..3

    constexpr float INV2PI = 0.15915493667125702f;
    float thC[8];
#pragma unroll
    for (int j = 0; j < 8; ++j) thC[j] = theta[j] * INV2PI;

    // ---- B: fragment-major base (fully coalesced 16B/lane loads) ----
    const unsigned short* wbase =
        PRECVT ? (WbF + ((size_t)wave * 4096 + lane) * 8) : nullptr;
    const float* wpf[4];
#pragma unroll
    for (int jn = 0; jn < 4; ++jn)
        wpf[jn] = W + (size_t)(n0 + jn * 16 + frow) * KD + fkg * 8;

    auto loadB = [&](int kf, short8* dst) {
#pragma unroll
        for (int jn = 0; jn < 4; ++jn) {
            if (PRECVT) {
                dst[jn] = *reinterpret_cast<const short8*>(
                    wbase + (size_t)(jn * 16 + kf) * 512);
            } else {
                float4 w0 = *reinterpret_cast<const float4*>(wpf[jn] + kf * 32);
                float4 w1 = *reinterpret_cast<const float4*>(wpf[jn] + kf * 32 + 4);
                short8 t8;
                t8[0] = (short)f2bf(w0.x); t8[1] = (short)f2bf(w0.y);
                t8[2] = (short)f2bf(w0.z); t8[3] = (short)f2bf(w0.w);
                t8[4] = (short)f2bf(w1.x); t8[5] = (short)f2bf(w1.y);
                t8[6] = (short)f2bf(w1.z); t8[7] = (short)f2bf(w1.w);
                dst[jn] = t8;
            }
        }
    };

    short8 bb[3][4];
    f32x4  acc[4][4];
#pragma unroll
    for (int i = 0; i < 4; ++i)
#pragma unroll
        for (int j = 0; j < 4; ++j) acc[i][j] = (f32x4)(0.0f);

    // ---- stage A tile: 64 rows x 512 cols; x loads + B(0,1) fly together ----
    {
        const int srow = tid >> 3;             // 0..63
        const int sc0  = (tid & 7) * 8;        // 0..56
        const float* xp = x + (size_t)(m0 + srow) * KD + sc0;
        float4 xv[8][2];
#pragma unroll
        for (int c = 0; c < 8; ++c) {
            xv[c][0] = *reinterpret_cast<const float4*>(xp + c * 64);
            xv[c][1] = *reinterpret_cast<const float4*>(xp + c * 64 + 4);
        }
        loadB(0, bb[0]);
        loadB(1, bb[1]);

        char* lb = reinterpret_cast<char*>(&Alds[0]) + srow * 1024;
        const int swz = (srow & 7) << 4;
#pragma unroll
        for (int c = 0; c < 8; ++c) {
            float v[8];
            *reinterpret_cast<float4*>(&v[0]) = xv[c][0];
            *reinterpret_cast<float4*>(&v[4]) = xv[c][1];
            short8 pk;
#pragma unroll
            for (int j = 0; j < 8; ++j)    // (sc0 + c*64) % 8 == 0 -> theta idx j
                pk[j] = (short)f2bf(fast_cos_rev(__builtin_fmaf(v[j], INV2PI, thC[j])));
            *reinterpret_cast<short8*>(lb + (((sc0 + c * 64) * 2) ^ swz)) = pk;
        }
    }
    __syncthreads();

    auto loadA = [&](int kf, short8* dst) {
#pragma unroll
        for (int i = 0; i < 4; ++i) {
            const int row  = i * 16 + frow;
            const int byte = row * 1024 + (((kf * 32 + fkg * 8) * 2) ^ ((row & 7) << 4));
            dst[i] = *reinterpret_cast<const short8*>(
                reinterpret_cast<const char*>(&Alds[0]) + byte);
        }
    };

    short8 aa[2][4];
    loadA(0, aa[0]);

    // ---- K loop: issue loads first, pin with sched_barrier, then MFMA ----
#pragma unroll
    for (int kf = 0; kf < NKF; ++kf) {
        if (kf + 1 < NKF) loadA(kf + 1, aa[(kf + 1) & 1]);
        if (kf + 2 < NKF) loadB(kf + 2, bb[(kf + 2) % 3]);
        __builtin_amdgcn_sched_barrier(0);
#pragma unroll
        for (int i = 0; i < 4; ++i)
#pragma unroll
            for (int jn = 0; jn < 4; ++jn)
                acc[i][jn] = __builtin_amdgcn_mfma_f32_16x16x32_bf16(
                    bb[kf % 3][jn], aa[kf & 1][i], acc[i][jn], 0, 0, 0);
    }

    // ---- epilogue: m = m0 + i*16 + frow, n = n0 + jn*16 + fkg*4 + r ----
    float* op = out + (size_t)(m0 + frow) * ND + n0 + fkg * 4;
#pragma unroll
    for (int i = 0; i < 4; ++i)
#pragma unroll
        for (int jn = 0; jn < 4; ++jn)
            *reinterpret_cast<f32x4*>(op + (size_t)(i * 16) * ND + jn * 16) =
                acc[i][jn];
}

extern "C" void kernel_launch(void* const* d_in, const int* in_sizes, int n_in,
                              void* d_out, int out_size, void* d_ws, size_t ws_size,
                              hipStream_t stream) {
    const float* x     = (const float*)d_in[0];
    const float* theta = (const float*)d_in[1];
    const float* W     = (const float*)d_in[2];
    float* out         = (float*)d_out;

    const int M      = in_sizes[0] / KD;       // 65536
    const int wElems = in_sizes[2];            // 512*512

    if (ws_size >= (size_t)wElems * sizeof(unsigned short)) {
        unsigned short* WbF = (unsigned short*)d_ws;
        cvt_w_frag<<<wElems / 8 / 256, 256, 0, stream>>>(W, WbF);
        fused_qgemm<true><<<M / BM, 512, 0, stream>>>(x, theta, W, WbF, out);
    } else {
        fused_qgemm<false><<<M / BM, 512, 0, stream>>>(x, theta, W, nullptr, out);
    }
}

// Round 7
// 76.905 us; speedup vs baseline: 4.4040x; 4.4040x over previous
//
#include <hip/hip_runtime.h>
#include <hip/hip_bf16.h>

// out[m, f] = sum_e cos(x[m, e] + theta[e & 7]) * W[f, e]
// M = 65536, N = K = 512.  bf16 MFMA GEMM, A = cos(x+theta) fused in staging.
//
// Block = 64x512 output stripe (full N -> x read exactly once from HBM).
// A: full 64x512 bf16 tile in 64 KB LDS (XOR-swizzled), ONE barrier.
// B: W pre-packed in d_ws in MFMA-fragment-major order -> every fragment load
//    is one fully-coalesced 16B/lane dwordx4 (8 x 128B lines per wave).
// K loop: fully unrolled 16 steps, 2-deep B / 1-deep A register prefetch,
// sched_barrier(0) per step pins issue order -> counted vmcnt/lgkmcnt waits.
// launch_bounds(512, 2): 256-VGPR cap -- BM=64 demand ~190 regs; the (512,4)
// 128-cap of round 6 forced a ~60-reg scratch spill (FETCH 514MB/WRITE 1GB).

typedef __attribute__((ext_vector_type(8))) short short8;   // 8 x bf16
typedef __attribute__((ext_vector_type(4))) float f32x4;    // MFMA acc frag

static constexpr int KD  = 512;
static constexpr int ND  = 512;
static constexpr int BM  = 64;
static constexpr int NKF = 16;           // K steps of 32

static __device__ __forceinline__ unsigned short f2bf(float f) {
    unsigned int b = __builtin_bit_cast(unsigned int, f);
    b += 0x7FFFu + ((b >> 16) & 1u);
    return (unsigned short)(b >> 16);
}

// cos via v_cos_f32: input in revolutions, explicit fract for range safety.
static __device__ __forceinline__ float fast_cos_rev(float rev) {
    float r = rev - __builtin_floorf(rev);
    float c;
    asm("v_cos_f32 %0, %1" : "=v"(c) : "v"(r));
    return c;
}

// Pack W into MFMA-fragment-major bf16:
//   WbF[((n_blk*16 + kf)*64 + lane)*8 + j] =
//       bf16( W[n_blk*16 + (lane&15)][kf*32 + (lane>>4)*8 + j] )
__global__ void cvt_w_frag(const float* __restrict__ W,
                           unsigned short* __restrict__ WbF) {
    const int i    = blockIdx.x * 256 + threadIdx.x;  // 0..32767 fragments
    const int lane = i & 63;
    const int kf   = (i >> 6) & 15;
    const int nblk = i >> 10;                         // 0..31
    const int row  = nblk * 16 + (lane & 15);         // f index
    const int col  = kf * 32 + (lane >> 4) * 8;       // e index
    const float* p = W + (size_t)row * KD + col;
    float4 w0 = *reinterpret_cast<const float4*>(p);
    float4 w1 = *reinterpret_cast<const float4*>(p + 4);
    short8 t8;
    t8[0] = (short)f2bf(w0.x); t8[1] = (short)f2bf(w0.y);
    t8[2] = (short)f2bf(w0.z); t8[3] = (short)f2bf(w0.w);
    t8[4] = (short)f2bf(w1.x); t8[5] = (short)f2bf(w1.y);
    t8[6] = (short)f2bf(w1.z); t8[7] = (short)f2bf(w1.w);
    *reinterpret_cast<short8*>(WbF + (size_t)i * 8) = t8;
}

template <bool PRECVT>
__global__ __launch_bounds__(512, 2)
void fused_qgemm(const float* __restrict__ x, const float* __restrict__ theta,
                 const float* __restrict__ W, const unsigned short* __restrict__ WbF,
                 float* __restrict__ out) {
    __shared__ unsigned short Alds[BM * KD];   // 64 KB, row pitch 1024 B, swizzled

    const int tid  = threadIdx.x;
    const int lane = tid & 63;
    const int wave = tid >> 6;                 // 0..7 -> n0 = wave*64
    const int m0   = blockIdx.x * BM;
    const int n0   = wave * 64;

    const int frow = lane & 15;                // fragment row/col index
    const int fkg  = lane >> 4;                // k-group 0..3

    constexpr float INV2PI = 0.15915493667125702f;
    float thC[8];
#pragma unroll
    for (int j = 0; j < 8; ++j) thC[j] = theta[j] * INV2PI;

    // ---- B: fragment-major base (fully coalesced 16B/lane loads) ----
    const unsigned short* wbase =
        PRECVT ? (WbF + ((size_t)wave * 4096 + lane) * 8) : nullptr;
    const float* wpf[4];
#pragma unroll
    for (int jn = 0; jn < 4; ++jn)
        wpf[jn] = W + (size_t)(n0 + jn * 16 + frow) * KD + fkg * 8;

    auto loadB = [&](int kf, short8* dst) {
#pragma unroll
        for (int jn = 0; jn < 4; ++jn) {
            if (PRECVT) {
                dst[jn] = *reinterpret_cast<const short8*>(
                    wbase + (size_t)(jn * 16 + kf) * 512);
            } else {
                float4 w0 = *reinterpret_cast<const float4*>(wpf[jn] + kf * 32);
                float4 w1 = *reinterpret_cast<const float4*>(wpf[jn] + kf * 32 + 4);
                short8 t8;
                t8[0] = (short)f2bf(w0.x); t8[1] = (short)f2bf(w0.y);
                t8[2] = (short)f2bf(w0.z); t8[3] = (short)f2bf(w0.w);
                t8[4] = (short)f2bf(w1.x); t8[5] = (short)f2bf(w1.y);
                t8[6] = (short)f2bf(w1.z); t8[7] = (short)f2bf(w1.w);
                dst[jn] = t8;
            }
        }
    };

    short8 bb[3][4];
    f32x4  acc[4][4];
#pragma unroll
    for (int i = 0; i < 4; ++i)
#pragma unroll
        for (int j = 0; j < 4; ++j) acc[i][j] = (f32x4)(0.0f);

    // ---- stage A tile: 64 rows x 512 cols; x loads + B(0,1) fly together ----
    {
        const int srow = tid >> 3;             // 0..63
        const int sc0  = (tid & 7) * 8;        // 0..56
        const float* xp = x + (size_t)(m0 + srow) * KD + sc0;
        float4 xv[8][2];
#pragma unroll
        for (int c = 0; c < 8; ++c) {
            xv[c][0] = *reinterpret_cast<const float4*>(xp + c * 64);
            xv[c][1] = *reinterpret_cast<const float4*>(xp + c * 64 + 4);
        }
        loadB(0, bb[0]);
        loadB(1, bb[1]);

        char* lb = reinterpret_cast<char*>(&Alds[0]) + srow * 1024;
        const int swz = (srow & 7) << 4;
#pragma unroll
        for (int c = 0; c < 8; ++c) {
            float v[8];
            *reinterpret_cast<float4*>(&v[0]) = xv[c][0];
            *reinterpret_cast<float4*>(&v[4]) = xv[c][1];
            short8 pk;
#pragma unroll
            for (int j = 0; j < 8; ++j)    // (sc0 + c*64) % 8 == 0 -> theta idx j
                pk[j] = (short)f2bf(fast_cos_rev(__builtin_fmaf(v[j], INV2PI, thC[j])));
            *reinterpret_cast<short8*>(lb + (((sc0 + c * 64) * 2) ^ swz)) = pk;
        }
    }
    __syncthreads();

    auto loadA = [&](int kf, short8* dst) {
#pragma unroll
        for (int i = 0; i < 4; ++i) {
            const int row  = i * 16 + frow;
            const int byte = row * 1024 + (((kf * 32 + fkg * 8) * 2) ^ ((row & 7) << 4));
            dst[i] = *reinterpret_cast<const short8*>(
                reinterpret_cast<const char*>(&Alds[0]) + byte);
        }
    };

    short8 aa[2][4];
    loadA(0, aa[0]);

    // ---- K loop: issue loads first, pin with sched_barrier, then MFMA ----
#pragma unroll
    for (int kf = 0; kf < NKF; ++kf) {
        if (kf + 1 < NKF) loadA(kf + 1, aa[(kf + 1) & 1]);
        if (kf + 2 < NKF) loadB(kf + 2, bb[(kf + 2) % 3]);
        __builtin_amdgcn_sched_barrier(0);
#pragma unroll
        for (int i = 0; i < 4; ++i)
#pragma unroll
            for (int jn = 0; jn < 4; ++jn)
                acc[i][jn] = __builtin_amdgcn_mfma_f32_16x16x32_bf16(
                    bb[kf % 3][jn], aa[kf & 1][i], acc[i][jn], 0, 0, 0);
    }

    // ---- epilogue: m = m0 + i*16 + frow, n = n0 + jn*16 + fkg*4 + r ----
    float* op = out + (size_t)(m0 + frow) * ND + n0 + fkg * 4;
#pragma unroll
    for (int i = 0; i < 4; ++i)
#pragma unroll
        for (int jn = 0; jn < 4; ++jn)
            *reinterpret_cast<f32x4*>(op + (size_t)(i * 16) * ND + jn * 16) =
                acc[i][jn];
}

extern "C" void kernel_launch(void* const* d_in, const int* in_sizes, int n_in,
                              void* d_out, int out_size, void* d_ws, size_t ws_size,
                              hipStream_t stream) {
    const float* x     = (const float*)d_in[0];
    const float* theta = (const float*)d_in[1];
    const float* W     = (const float*)d_in[2];
    float* out         = (float*)d_out;

    const int M      = in_sizes[0] / KD;       // 65536
    const int wElems = in_sizes[2];            // 512*512

    if (ws_size >= (size_t)wElems * sizeof(unsigned short)) {
        unsigned short* WbF = (unsigned short*)d_ws;
        cvt_w_frag<<<wElems / 8 / 256, 256, 0, stream>>>(W, WbF);
        fused_qgemm<true><<<M / BM, 512, 0, stream>>>(x, theta, W, WbF, out);
    } else {
        fused_qgemm<false><<<M / BM, 512, 0, stream>>>(x, theta, W, nullptr, out);
    }
}